// Round 2
// baseline (443.760 us; speedup 1.0000x reference)
//
#include <hip/hip_runtime.h>
#include <stdint.h>

#define NEGF (-1e30f)

typedef unsigned short ushort_t;
typedef unsigned char uchar_t;
typedef __attribute__((ext_vector_type(4))) float f32x4;
typedef __attribute__((ext_vector_type(8))) int v8i32;

constexpr int cB = 4, cT = 256, cU = 64, cU1 = 65, cV = 1024, cF = 80, cH = 512, cJ = 512;
constexpr int cM = cB * cT * cU1; // 66560
constexpr int cTU = cT * cU1;     // 16640 (per-batch (u,t) plane: u*256+t)
constexpr float LOG2E = 1.4426950408889634f;

// Padé(2,2) tanh + clamp: max err ~0.016, far below fp8-e4m3 half-step; no v_exp.
__device__ __forceinline__ float tanh_fast(float x){
  float t = x * x;
  float num = x * (27.f + t);
  float den = fmaf(9.f, t, 27.f);
  float r = num * __builtin_amdgcn_rcpf(den);
  return fminf(1.f, fmaxf(-1.f, r));
}

// log2-domain logadd: v_exp_f32/v_log_f32 ARE base-2 -> no ln2 scaling muls.
__device__ __forceinline__ float logadd2(float x, float y){
  float m = fmaxf(x, y);
  return m + __builtin_amdgcn_logf(1.f + __builtin_amdgcn_exp2f(-fabsf(x - y)));
}

__device__ __forceinline__ int pk8(float a, float b, float c, float d){
  int v = __builtin_amdgcn_cvt_pk_fp8_f32(a, b, 0, false);
  v = __builtin_amdgcn_cvt_pk_fp8_f32(c, d, v, true);
  return v;
}

// ------------- fused prologue: 4 independent jobs in one dispatch -------------
// bid 0..255  : e[4 rows] = (inputs @ W_enc) @ W_jenc, block-local two-stage
// bid 256..385: dmatb(260,512) = emb[padded] @ W_jdec + b_j
// bid 386..417: WTf8 fp8 K=128 fragment-order transpose of 32*W_out
//               layout: [strip8][kblk4][nt16_8][lane64*32B] (2048 B fragments)
// bid 418..482: zero S[cM]; bid 418 also zeroes out[0] (k_dp atomic target)
__global__ __launch_bounds__(256) void k_pre(
    const float* __restrict__ inputs,
    const float* __restrict__ W_enc, const float* __restrict__ W_jenc,
    const float* __restrict__ emb, const int* __restrict__ targets,
    const float* __restrict__ W_jdec, const float* __restrict__ b_j,
    float* __restrict__ dmatb, float* __restrict__ e,
    const float* __restrict__ W_out, uchar_t* __restrict__ WTf8,
    float* __restrict__ S, float* __restrict__ out_loss)
{
  __shared__ float sA[4][512];
  __shared__ float sIn[4][80];
  int bid = blockIdx.x;
  int tid = threadIdx.x;

  if (bid < 256){
    // ---- e rows m0..m0+3 ----
    int m0 = bid * 4;
    // r20 BUG FIX: 320 elements with 256 threads needs a strided loop (the
    // single `if (tid < 320)` left sIn[3][16..79] uninitialized -> absmax 16).
    for (int i = tid; i < 320; i += 256)
      sIn[i / 80][i % 80] = inputs[m0 * 80 + i];
    __syncthreads();
    int c0 = tid, c1 = tid + 256;
    float a00 = 0.f, a01 = 0.f, a10 = 0.f, a11 = 0.f;
    float a20 = 0.f, a21 = 0.f, a30 = 0.f, a31 = 0.f;
#pragma unroll 8
    for (int k = 0; k < 80; k++){
      float w0 = W_enc[(size_t)k * 512 + c0];
      float w1 = W_enc[(size_t)k * 512 + c1];
      a00 = fmaf(sIn[0][k], w0, a00); a01 = fmaf(sIn[0][k], w1, a01);
      a10 = fmaf(sIn[1][k], w0, a10); a11 = fmaf(sIn[1][k], w1, a11);
      a20 = fmaf(sIn[2][k], w0, a20); a21 = fmaf(sIn[2][k], w1, a21);
      a30 = fmaf(sIn[3][k], w0, a30); a31 = fmaf(sIn[3][k], w1, a31);
    }
    sA[0][c0] = a00; sA[0][c1] = a01;
    sA[1][c0] = a10; sA[1][c1] = a11;
    sA[2][c0] = a20; sA[2][c1] = a21;
    sA[3][c0] = a30; sA[3][c1] = a31;
    __syncthreads();
    float b00 = 0.f, b01 = 0.f, b10 = 0.f, b11 = 0.f;
    float b20 = 0.f, b21 = 0.f, b30 = 0.f, b31 = 0.f;
#pragma unroll 8
    for (int k = 0; k < 512; k++){
      float w0 = W_jenc[(size_t)k * 512 + c0];
      float w1 = W_jenc[(size_t)k * 512 + c1];
      b00 = fmaf(sA[0][k], w0, b00); b01 = fmaf(sA[0][k], w1, b01);
      b10 = fmaf(sA[1][k], w0, b10); b11 = fmaf(sA[1][k], w1, b11);
      b20 = fmaf(sA[2][k], w0, b20); b21 = fmaf(sA[2][k], w1, b21);
      b30 = fmaf(sA[3][k], w0, b30); b31 = fmaf(sA[3][k], w1, b31);
    }
    e[(size_t)(m0 + 0) * 512 + c0] = b00; e[(size_t)(m0 + 0) * 512 + c1] = b01;
    e[(size_t)(m0 + 1) * 512 + c0] = b10; e[(size_t)(m0 + 1) * 512 + c1] = b11;
    e[(size_t)(m0 + 2) * 512 + c0] = b20; e[(size_t)(m0 + 2) * 512 + c1] = b21;
    e[(size_t)(m0 + 3) * 512 + c0] = b30; e[(size_t)(m0 + 3) * 512 + c1] = b31;
  } else if (bid < 386){
    // ---- dmatb = emb[padded] @ W_jdec + b_j ----
    int id = bid - 256;                  // 0..129
    int bx = id & 1, by = id >> 1;
    int m0 = by * 4;
    int col = bx * 256 + tid;
    for (int i = tid; i < 4 * 512; i += 256){
      int r = i >> 9, c = i & 511;
      int row = m0 + r;
      int b = row / cU1, u = row % cU1;
      int src = (u == 0) ? 0 : targets[b * cU + (u - 1)];
      sA[r][c] = emb[(size_t)src * cH + c];
    }
    __syncthreads();
    float a0 = 0.f, a1 = 0.f, a2 = 0.f, a3 = 0.f;
#pragma unroll 8
    for (int k = 0; k < 512; k++){
      float bv = W_jdec[(size_t)k * cJ + col];
      a0 = fmaf(sA[0][k], bv, a0);
      a1 = fmaf(sA[1][k], bv, a1);
      a2 = fmaf(sA[2][k], bv, a2);
      a3 = fmaf(sA[3][k], bv, a3);
    }
    float bb = b_j[col];
    dmatb[(size_t)(m0 + 0) * cJ + col] = a0 + bb;
    dmatb[(size_t)(m0 + 1) * cJ + col] = a1 + bb;
    dmatb[(size_t)(m0 + 2) * cJ + col] = a2 + bb;
    dmatb[(size_t)(m0 + 3) * cJ + col] = a3 + bb;
  } else if (bid < 418){
    // ---- WTf8 K=128 fragments: lane holds col=c16, k = kblk*128+quad*32+0..31 ----
    int id = bid - 386;                  // 0..31
    int strip = id >> 2, kblk = id & 3;
    int lane = tid & 63, nth = tid >> 6;
    int c16 = lane & 15, quad = lane >> 4;
    int jbase = kblk * 128 + quad * 32;
#pragma unroll
    for (int i = 0; i < 2; i++){
      int nt16 = nth * 2 + i;
      int n = strip * 128 + nt16 * 16 + c16;
      unsigned int p[8];
#pragma unroll
      for (int d = 0; d < 8; d++){
        int j0 = jbase + d * 4;
        float w0 = W_out[(size_t)(j0 + 0) * cV + n] * 32.f;
        float w1 = W_out[(size_t)(j0 + 1) * cV + n] * 32.f;
        float w2 = W_out[(size_t)(j0 + 2) * cV + n] * 32.f;
        float w3 = W_out[(size_t)(j0 + 3) * cV + n] * 32.f;
        p[d] = (unsigned)pk8(w0, w1, w2, w3);
      }
      uchar_t* dst = WTf8 + ((size_t)((strip * 4 + kblk) * 8 + nt16)) * 2048 + lane * 32;
      uint4 qa; qa.x = p[0]; qa.y = p[1]; qa.z = p[2]; qa.w = p[3];
      uint4 qb; qb.x = p[4]; qb.y = p[5]; qb.z = p[6]; qb.w = p[7];
      *(uint4*)dst = qa;
      *(uint4*)(dst + 16) = qb;
    }
  } else {
    // ---- zero S: 65 blocks x 256 thr x 4 floats = 66560 ----
    int i = (bid - 418) * 1024 + tid * 4;
    float4 z; z.x = 0.f; z.y = 0.f; z.z = 0.f; z.w = 0.f;
    *(float4*)(S + i) = z;
    if (bid == 418 && tid == 0) out_loss[0] = 0.f;
  }
}

// ------------- H fp8 K=128 fragment-order, coalesced via LDS bounce -------------
// Hbf8 layout per bm tile: [kblk4][mg8][lane64*32B] (2048 B fragments);
// lane holds row = mg*16 + c16, k = kblk*128 + quad*32 + 0..31.
__global__ __launch_bounds__(256) void k_hf(const float* __restrict__ e,
                                            const float* __restrict__ dmatb,
                                            uchar_t* __restrict__ Hbf8){
  __shared__ uchar_t sH[16 * 520];    // 16 rows x 512 B, pad 8 B (8B-aligned reads)
  int tid = threadIdx.x;
  int wid = tid >> 6, lane = tid & 63;
  int c16 = lane & 15, quad = lane >> 4;
  int bm = blockIdx.x;
  int bu = bm >> 1, thalf = bm & 1;
  int b = bu / cU1;
  int t0 = thalf * 128;

  float dj[8];
  const float4* dp = (const float4*)(dmatb + (size_t)bu * cJ + lane * 8);
  float4 dA = dp[0], dB = dp[1];
  dj[0] = dA.x; dj[1] = dA.y; dj[2] = dA.z; dj[3] = dA.w;
  dj[4] = dB.x; dj[5] = dB.y; dj[6] = dB.z; dj[7] = dB.w;

  const float* erow0 = e + ((size_t)(b * cT + t0)) * cJ + lane * 8;
  uchar_t* outb = Hbf8 + (size_t)bm * 65536 + lane * 32;

  for (int mg = 0; mg < 8; mg++){
#pragma unroll
    for (int rr = 0; rr < 4; rr++){
      int rloc = wid * 4 + rr;
      const float* ep = erow0 + ((size_t)(mg * 16 + rloc)) * cJ;
      float4 e0 = *(const float4*)ep;
      float4 e1 = *(const float4*)(ep + 4);
      int v0 = pk8(tanh_fast(e0.x + dj[0]), tanh_fast(e0.y + dj[1]),
                   tanh_fast(e0.z + dj[2]), tanh_fast(e0.w + dj[3]));
      int v1 = pk8(tanh_fast(e1.x + dj[4]), tanh_fast(e1.y + dj[5]),
                   tanh_fast(e1.z + dj[6]), tanh_fast(e1.w + dj[7]));
      uint2 pk; pk.x = (unsigned)v0; pk.y = (unsigned)v1;
      *(uint2*)(sH + rloc * 520 + lane * 8) = pk;
    }
    __syncthreads();
    {
      int kblk = wid;                      // one K=128 fragment per wave
      const uchar_t* src = sH + c16 * 520 + kblk * 128 + quad * 32;
      uint2 q0 = *(const uint2*)(src);
      uint2 q1 = *(const uint2*)(src + 8);
      uint2 q2 = *(const uint2*)(src + 16);
      uint2 q3 = *(const uint2*)(src + 24);
      uint4 qa; qa.x = q0.x; qa.y = q0.y; qa.z = q1.x; qa.w = q1.y;
      uint4 qb; qb.x = q2.x; qb.y = q2.y; qb.z = q3.x; qb.w = q3.y;
      uchar_t* dst = outb + ((size_t)(kblk * 8 + mg)) * 2048;
      *(uint4*)(dst) = qa;
      *(uint4*)(dst + 16) = qb;
    }
    __syncthreads();
  }
}

// ------------- joint GEMM MX-fp8 K=128 (unit scales): 64x64 wave tile -------------
// mfma_scale_f32_16x16x128_f8f6f4 runs at 2x the non-scaled fp8 rate; scale
// bytes 0x7F = e8m0 1.0 (replicated so any opsel selection is 1.0).
// Epilogue in log2 domain: exp2 directly, log2e folded into descale/b_out;
// blank_g/lbl_g now hold log2-domain logits (k_dp consumes them as such).
__global__ __launch_bounds__(256, 3) void k_joint(
    const uchar_t* __restrict__ Hbf8, const uchar_t* __restrict__ WTf8,
    const float* __restrict__ b_out, const int* __restrict__ targets,
    float* __restrict__ S,
    float* __restrict__ blank_g, float* __restrict__ lbl_g)
{
  __shared__ float redS[2][128];

  int tid = threadIdx.x;
  int wid = tid >> 6, lane = tid & 63;
  int quad = lane >> 4, c16 = lane & 15;
  int wm = wid & 1, wn = wid >> 1;
  int bid = blockIdx.x;
  int bm = ((bid >> 6) << 3) + (bid & 7);
  int bn = (bid >> 3) & 7;                       // 128-col strip
  int bu = bm >> 1, thalf = bm & 1;
  int b = bu / cU1, u = bu - b * cU1;
  int tg = (u < cU) ? targets[b * cU + u] : -1;
  int lin0 = bu * cT + thalf * 128;              // (b,u,t)-linear base

  f32x4 acc[4][4];
#pragma unroll
  for (int i = 0; i < 4; i++)
#pragma unroll
    for (int j = 0; j < 4; j++)
      acc[i][j] = (f32x4){0.f, 0.f, 0.f, 0.f};

  const uchar_t* aP = Hbf8 + (size_t)bm * 65536 + (size_t)(wm * 4) * 2048 + lane * 32;
  const uchar_t* bP = WTf8 + (size_t)bn * 65536 + (size_t)(wn * 4) * 2048 + lane * 32;

#pragma unroll
  for (int kblk = 0; kblk < 4; kblk++){
    v8i32 af[4], bf[4];
#pragma unroll
    for (int mt = 0; mt < 4; mt++)
      af[mt] = *(const v8i32*)(aP + (size_t)kblk * 16384 + mt * 2048);
#pragma unroll
    for (int nt = 0; nt < 4; nt++)
      bf[nt] = *(const v8i32*)(bP + (size_t)kblk * 16384 + nt * 2048);
#pragma unroll
    for (int mt = 0; mt < 4; mt++)
#pragma unroll
      for (int nt = 0; nt < 4; nt++)
        acc[mt][nt] = __builtin_amdgcn_mfma_scale_f32_16x16x128_f8f6f4(
            af[mt], bf[nt], acc[mt][nt], 0, 0,
            0, 0x7F7F7F7F, 0, 0x7F7F7F7F);
  }

  float bv[4];
#pragma unroll
  for (int nt = 0; nt < 4; nt++) bv[nt] = b_out[bn * 128 + (wn * 4 + nt) * 16 + c16] * LOG2E;

  bool ownL = (tg >= 0) && ((tg >> 7) == bn) && (((tg >> 6) & 1) == wn);
  int ntO = (tg >> 4) & 3;
  int tgc = tg & 15;
  const float descale2 = LOG2E / 32.f;  // undo *32 on W_out fp8 AND go log2-domain

#pragma unroll
  for (int mt = 0; mt < 4; mt++){
#pragma unroll
    for (int r = 0; r < 4; r++){
      int rl = wm * 64 + mt * 16 + quad * 4 + r;  // C/D: col=lane&15, row=quad*4+reg (m89)
      float l[4];
#pragma unroll
      for (int nt = 0; nt < 4; nt++) l[nt] = fmaf(acc[mt][nt][r], descale2, bv[nt]);
      if (bn == 0 && wn == 0 && c16 == 0) blank_g[lin0 + rl] = l[0];
      if (ownL && c16 == tgc){
        float v = l[0];
#pragma unroll
        for (int k = 1; k < 4; k++) v = (ntO == k) ? l[k] : v;
        lbl_g[lin0 + rl] = v;
      }
      float s = __builtin_amdgcn_exp2f(l[0]) + __builtin_amdgcn_exp2f(l[1])
              + __builtin_amdgcn_exp2f(l[2]) + __builtin_amdgcn_exp2f(l[3]);
      s += __shfl_xor(s, 1, 64);
      s += __shfl_xor(s, 2, 64);
      s += __shfl_xor(s, 4, 64);
      s += __shfl_xor(s, 8, 64);
      if (c16 == 0) redS[wn][rl] = s;
    }
  }
  __syncthreads();
  if (tid < 128)
    atomicAdd(&S[lin0 + tid], redS[0][tid] + redS[1][tid]);
}

// ------------- RNN-T alpha DP: SKIP-2 diagonals, log2 domain, fused-LSE staging -------------
// blank_g/lbl_g arrive ALREADY in log2 domain (k_joint epilogue) -> staging is
// just x - log2(S). Everything else as the verified r1 version.
__global__ __launch_bounds__(256) void k_dp(
    const float* __restrict__ S, const float* __restrict__ blank_g,
    const float* __restrict__ lbl_g,
    const int* __restrict__ in_len, const int* __restrict__ tgt_len,
    float* __restrict__ out)
{
  __shared__ float sbb[cTU];   // 65 KB, (u,t): index u*256+t  (log2 domain)
  __shared__ float slb[cTU];   // 65 KB
  __shared__ float sS[256];    // alpha[t][63] history (lane 63)
  int b = blockIdx.x;
  int tl  = tgt_len[b];                // 32..64
  size_t base = (size_t)b * cTU;
  for (int i = threadIdx.x; i < cTU / 4; i += 256){
    int row = i >> 6;                  // float4 never crosses a 256-elem row
    if (row > tl) continue;            // rows > tl unread by any live lane
    float4 sv = ((const float4*)(S + base))[i];
    float4 bvv = ((const float4*)(blank_g + base))[i];
    float4 ls;
    ls.x = __builtin_amdgcn_logf(sv.x); ls.y = __builtin_amdgcn_logf(sv.y);
    ls.z = __builtin_amdgcn_logf(sv.z); ls.w = __builtin_amdgcn_logf(sv.w);
    float4 bo;
    bo.x = bvv.x - ls.x; bo.y = bvv.y - ls.y;
    bo.z = bvv.z - ls.z; bo.w = bvv.w - ls.w;
    ((float4*)sbb)[i] = bo;
    float4 lo;
    if (row < tl){
      float4 lv = ((const float4*)(lbl_g + base))[i];
      lo.x = lv.x - ls.x; lo.y = lv.y - ls.y;
      lo.z = lv.z - ls.z; lo.w = lv.w - ls.w;
    } else {
      lo.x = NEGF; lo.y = NEGF; lo.z = NEGF; lo.w = NEGF;
    }
    ((float4*)slb)[i] = lo;
  }
  __syncthreads();
  if (threadIdx.x >= 64) return;

  int u = threadIdx.x;                 // 0..63
  int til = in_len[b] - 1;
  bool cap64 = (tl == 64);
  bool isTL = (u == tl);
  const float* pbu  = sbb + (u << 8);
  const float* pbu1 = sbb + (((u >= 1) ? u - 1 : 0) << 8);
  const float* plu1 = slb + (((u >= 1) ? u - 1 : 0) << 8);
  const float* plu2 = slb + (((u >= 2) ? u - 2 : 0) << 8);
  bool u1 = (u >= 1), u2 = (u >= 2);
  float fb = pbu[til];                 // blank at (u, til); used by lane tl only
  int shA1 = (u - 1) << 2;             // bpermute byte addrs; underflow wraps to
  int shA2 = (u - 2) << 2;             // lane 63 -> value killed by NEG masking

  float A = (u == 0) ? 0.f : NEGF;     // alpha on even diagonal d = 2g (log2)
  float res = 0.f;

  auto ld = [&](const float* p, int i, bool ok) -> float {
    float x = p[i & 255];              // wrap stays inside sbb/slb
    return (ok & ((unsigned)i < 256u)) ? x : NEGF;
  };

  int i0 = -u;
  float o0 = ld(pbu,  i0,     true);   // bb[t-2][u]
  float o1 = ld(pbu,  i0 + 1, true);   // bb[t-1][u]
  float o2 = ld(plu1, i0 + 1, u1);     // lb[t-1][u-1]
  float o3 = ld(pbu1, i0 + 1, u1);     // bb[t-1][u-1]
  float o4 = ld(plu1, i0 + 2, u1);     // lb[t][u-1]
  float o5 = ld(plu2, i0 + 2, u2);     // lb[t][u-2]

#pragma unroll 3
  for (int g = 0; g < 159; g++){
    // shuffles FIRST (depend on prev A) so the prefetch reads below stay behind
    // them in lgkm order -> waiting for up1/up2 is lgkmcnt(6), not a full drain
    float up1 = __int_as_float(__builtin_amdgcn_ds_bpermute(shA1, __float_as_int(A)));
    float up2 = __int_as_float(__builtin_amdgcn_ds_bpermute(shA2, __float_as_int(A)));

    int i0n = i0 + 2;
    float n0 = ld(pbu,  i0n,     true);
    float n1 = ld(pbu,  i0n + 1, true);
    float n2 = ld(plu1, i0n + 1, u1);
    float n3 = ld(pbu1, i0n + 1, u1);
    float n4 = ld(plu1, i0n + 2, u1);
    float n5 = ld(plu2, i0n + 2, u2);

    float C0 = o0 + o1;
    float C1 = logadd2(o2 + o1, o3 + o4);
    float C2 = o5 + o4;

    float am0 = A + o0, am1 = up1 + o2;
    float Amid = logadd2(am0, am1);
    bool tv1 = ((unsigned)(i0 + 1) < 256u);
    Amid = tv1 ? Amid : NEGF;

    float a0 = A + C0, a1 = up1 + C1, a2 = up2 + C2;
    float m3 = fmaxf(fmaxf(a0, a1), a2);          // v_max3
    float s3 = __builtin_amdgcn_exp2f(a0 - m3) + __builtin_amdgcn_exp2f(a1 - m3)
             + __builtin_amdgcn_exp2f(a2 - m3);
    float Anew = m3 + __builtin_amdgcn_logf(s3);
    bool tv2 = ((unsigned)(i0 + 2) < 256u);
    Anew = tv2 ? Anew : NEGF;

    if (isTL && (i0 + 1) == til) res = Amid + fb;
    if (isTL && (i0 + 2) == til) res = Anew + fb;
    if (u == 63){
      if (tv1) sS[i0 + 1] = Amid;
      if (tv2) sS[i0 + 2] = Anew;
    }
    A = Anew;
    i0 = i0n;
    o0 = n0; o1 = n1; o2 = n2; o3 = n3; o4 = n4; o5 = n5;
  }

  if (cap64){
    const float* pb64 = sbb + (64 << 8);
    const float* pl63 = slb + (63 << 8);
    float A64 = sS[0] + pl63[0];       // alpha[0][64]
    for (int t = 1; t <= til; t++)
      A64 = logadd2(A64 + pb64[t - 1], sS[t] + pl63[t]);
    if (u == 0) res = A64 + pb64[til];
  }

  // butterfly-sum broadcasts the single captured value (others hold 0)
  res += __shfl_xor(res, 1, 64);
  res += __shfl_xor(res, 2, 64);
  res += __shfl_xor(res, 4, 64);
  res += __shfl_xor(res, 8, 64);
  res += __shfl_xor(res, 16, 64);
  res += __shfl_xor(res, 32, 64);
  if (u == 0) atomicAdd(out, -0.17328679513998632f * res);  // -0.25 * ln2 (log2->ln)
}

extern "C" void kernel_launch(void* const* d_in, const int* in_sizes, int n_in,
                              void* d_out, int out_size, void* d_ws, size_t ws_size,
                              hipStream_t stream)
{
  (void)in_sizes; (void)n_in; (void)out_size; (void)ws_size;
  const float* inputs = (const float*)d_in[0];   // (4,256,80)
  const float* W_enc  = (const float*)d_in[1];   // (80,512)
  const float* emb    = (const float*)d_in[2];   // (1024,512)
  const float* W_jenc = (const float*)d_in[3];   // (512,512)
  const float* W_jdec = (const float*)d_in[4];   // (512,512)
  const float* b_j    = (const float*)d_in[5];   // (512)
  const float* W_out  = (const float*)d_in[6];   // (512,1024)
  const float* b_out  = (const float*)d_in[7];   // (1024)
  const int* targets  = (const int*)d_in[8];     // (4,64)
  const int* in_len   = (const int*)d_in[9];     // (4)
  const int* tgt_len  = (const int*)d_in[10];    // (4)

  char* w = (char*)d_ws;
  auto alloc = [&](size_t bytes){ char* p = w; w += (bytes + 255) & ~(size_t)255; return p; };
  float* e       = (float*)alloc((size_t)1024 * 512 * 4);
  float* dmatb   = (float*)alloc((size_t)260 * 512 * 4);
  float* blank_g = (float*)alloc((size_t)cM * 4);
  float* lbl_g   = (float*)alloc((size_t)cM * 4);
  float* S       = (float*)alloc((size_t)cM * 4);
  uchar_t* Hbf8  = (uchar_t*)alloc((size_t)520 * 65536);
  uchar_t* WTf8  = (uchar_t*)alloc((size_t)8 * 65536);

  k_pre<<<483, 256, 0, stream>>>(inputs, W_enc, W_jenc, emb, targets, W_jdec, b_j,
                                 dmatb, e, W_out, WTf8, S, (float*)d_out);
  k_hf<<<520, 256, 0, stream>>>(e, dmatb, Hbf8);
  k_joint<<<4160, 256, 0, stream>>>(Hbf8, WTf8, b_out, targets, S, blank_g, lbl_g);
  k_dp<<<4, 256, 0, stream>>>(S, blank_g, lbl_g, in_len, tgt_len, (float*)d_out);
}

// Round 3
// 220.979 us; speedup vs baseline: 2.0082x; 2.0082x over previous
//
#include <hip/hip_runtime.h>
#include <stdint.h>

#define NEGF (-1e30f)

typedef unsigned short ushort_t;
typedef unsigned char uchar_t;
typedef __attribute__((ext_vector_type(4))) float f32x4;
typedef __attribute__((ext_vector_type(8))) int v8i32;

constexpr int cB = 4, cT = 256, cU = 64, cU1 = 65, cV = 1024, cF = 80, cH = 512, cJ = 512;
constexpr int cM = cB * cT * cU1; // 66560
constexpr int cTU = cT * cU1;     // 16640 (per-batch (u,t) plane: u*256+t)
constexpr float LOG2E = 1.4426950408889634f;

// Padé(2,2) tanh + clamp: max err ~0.016, far below fp8-e4m3 half-step; no v_exp.
__device__ __forceinline__ float tanh_fast(float x){
  float t = x * x;
  float num = x * (27.f + t);
  float den = fmaf(9.f, t, 27.f);
  float r = num * __builtin_amdgcn_rcpf(den);
  return fminf(1.f, fmaxf(-1.f, r));
}

// log2-domain logadd: v_exp_f32/v_log_f32 ARE base-2 -> no ln2 scaling muls.
__device__ __forceinline__ float logadd2(float x, float y){
  float m = fmaxf(x, y);
  return m + __builtin_amdgcn_logf(1.f + __builtin_amdgcn_exp2f(-fabsf(x - y)));
}

__device__ __forceinline__ int pk8(float a, float b, float c, float d){
  int v = __builtin_amdgcn_cvt_pk_fp8_f32(a, b, 0, false);
  v = __builtin_amdgcn_cvt_pk_fp8_f32(c, d, v, true);
  return v;
}

// ------------- fused prologue: 4 independent jobs in one dispatch -------------
// bid 0..255  : e[4 rows] = (inputs @ W_enc) @ W_jenc, block-local two-stage
// bid 256..385: dmatb(260,512) = emb[padded] @ W_jdec + b_j
// bid 386..417: WTf8 fp8 K=128 fragment-order transpose of 32*W_out
//               layout: [strip8][kblk4][nt16_8][lane64*32B] (2048 B fragments)
// bid 418..482: zero S[cM]; bid 418 also zeroes out[0] (k_dp atomic target)
__global__ __launch_bounds__(256) void k_pre(
    const float* __restrict__ inputs,
    const float* __restrict__ W_enc, const float* __restrict__ W_jenc,
    const float* __restrict__ emb, const int* __restrict__ targets,
    const float* __restrict__ W_jdec, const float* __restrict__ b_j,
    float* __restrict__ dmatb, float* __restrict__ e,
    const float* __restrict__ W_out, uchar_t* __restrict__ WTf8,
    float* __restrict__ S, float* __restrict__ out_loss)
{
  __shared__ float sA[4][512];
  __shared__ float sIn[4][80];
  int bid = blockIdx.x;
  int tid = threadIdx.x;

  if (bid < 256){
    // ---- e rows m0..m0+3 ----
    int m0 = bid * 4;
    // r20 BUG FIX: 320 elements with 256 threads needs a strided loop (the
    // single `if (tid < 320)` left sIn[3][16..79] uninitialized -> absmax 16).
    for (int i = tid; i < 320; i += 256)
      sIn[i / 80][i % 80] = inputs[m0 * 80 + i];
    __syncthreads();
    int c0 = tid, c1 = tid + 256;
    float a00 = 0.f, a01 = 0.f, a10 = 0.f, a11 = 0.f;
    float a20 = 0.f, a21 = 0.f, a30 = 0.f, a31 = 0.f;
#pragma unroll 8
    for (int k = 0; k < 80; k++){
      float w0 = W_enc[(size_t)k * 512 + c0];
      float w1 = W_enc[(size_t)k * 512 + c1];
      a00 = fmaf(sIn[0][k], w0, a00); a01 = fmaf(sIn[0][k], w1, a01);
      a10 = fmaf(sIn[1][k], w0, a10); a11 = fmaf(sIn[1][k], w1, a11);
      a20 = fmaf(sIn[2][k], w0, a20); a21 = fmaf(sIn[2][k], w1, a21);
      a30 = fmaf(sIn[3][k], w0, a30); a31 = fmaf(sIn[3][k], w1, a31);
    }
    sA[0][c0] = a00; sA[0][c1] = a01;
    sA[1][c0] = a10; sA[1][c1] = a11;
    sA[2][c0] = a20; sA[2][c1] = a21;
    sA[3][c0] = a30; sA[3][c1] = a31;
    __syncthreads();
    float b00 = 0.f, b01 = 0.f, b10 = 0.f, b11 = 0.f;
    float b20 = 0.f, b21 = 0.f, b30 = 0.f, b31 = 0.f;
#pragma unroll 8
    for (int k = 0; k < 512; k++){
      float w0 = W_jenc[(size_t)k * 512 + c0];
      float w1 = W_jenc[(size_t)k * 512 + c1];
      b00 = fmaf(sA[0][k], w0, b00); b01 = fmaf(sA[0][k], w1, b01);
      b10 = fmaf(sA[1][k], w0, b10); b11 = fmaf(sA[1][k], w1, b11);
      b20 = fmaf(sA[2][k], w0, b20); b21 = fmaf(sA[2][k], w1, b21);
      b30 = fmaf(sA[3][k], w0, b30); b31 = fmaf(sA[3][k], w1, b31);
    }
    e[(size_t)(m0 + 0) * 512 + c0] = b00; e[(size_t)(m0 + 0) * 512 + c1] = b01;
    e[(size_t)(m0 + 1) * 512 + c0] = b10; e[(size_t)(m0 + 1) * 512 + c1] = b11;
    e[(size_t)(m0 + 2) * 512 + c0] = b20; e[(size_t)(m0 + 2) * 512 + c1] = b21;
    e[(size_t)(m0 + 3) * 512 + c0] = b30; e[(size_t)(m0 + 3) * 512 + c1] = b31;
  } else if (bid < 386){
    // ---- dmatb = emb[padded] @ W_jdec + b_j ----
    int id = bid - 256;                  // 0..129
    int bx = id & 1, by = id >> 1;
    int m0 = by * 4;
    int col = bx * 256 + tid;
    for (int i = tid; i < 4 * 512; i += 256){
      int r = i >> 9, c = i & 511;
      int row = m0 + r;
      int b = row / cU1, u = row % cU1;
      int src = (u == 0) ? 0 : targets[b * cU + (u - 1)];
      sA[r][c] = emb[(size_t)src * cH + c];
    }
    __syncthreads();
    float a0 = 0.f, a1 = 0.f, a2 = 0.f, a3 = 0.f;
#pragma unroll 8
    for (int k = 0; k < 512; k++){
      float bv = W_jdec[(size_t)k * cJ + col];
      a0 = fmaf(sA[0][k], bv, a0);
      a1 = fmaf(sA[1][k], bv, a1);
      a2 = fmaf(sA[2][k], bv, a2);
      a3 = fmaf(sA[3][k], bv, a3);
    }
    float bb = b_j[col];
    dmatb[(size_t)(m0 + 0) * cJ + col] = a0 + bb;
    dmatb[(size_t)(m0 + 1) * cJ + col] = a1 + bb;
    dmatb[(size_t)(m0 + 2) * cJ + col] = a2 + bb;
    dmatb[(size_t)(m0 + 3) * cJ + col] = a3 + bb;
  } else if (bid < 418){
    // ---- WTf8 K=128 fragments: lane holds col=c16, k = kblk*128+quad*32+0..31 ----
    int id = bid - 386;                  // 0..31
    int strip = id >> 2, kblk = id & 3;
    int lane = tid & 63, nth = tid >> 6;
    int c16 = lane & 15, quad = lane >> 4;
    int jbase = kblk * 128 + quad * 32;
#pragma unroll
    for (int i = 0; i < 2; i++){
      int nt16 = nth * 2 + i;
      int n = strip * 128 + nt16 * 16 + c16;
      unsigned int p[8];
#pragma unroll
      for (int d = 0; d < 8; d++){
        int j0 = jbase + d * 4;
        float w0 = W_out[(size_t)(j0 + 0) * cV + n] * 32.f;
        float w1 = W_out[(size_t)(j0 + 1) * cV + n] * 32.f;
        float w2 = W_out[(size_t)(j0 + 2) * cV + n] * 32.f;
        float w3 = W_out[(size_t)(j0 + 3) * cV + n] * 32.f;
        p[d] = (unsigned)pk8(w0, w1, w2, w3);
      }
      uchar_t* dst = WTf8 + ((size_t)((strip * 4 + kblk) * 8 + nt16)) * 2048 + lane * 32;
      uint4 qa; qa.x = p[0]; qa.y = p[1]; qa.z = p[2]; qa.w = p[3];
      uint4 qb; qb.x = p[4]; qb.y = p[5]; qb.z = p[6]; qb.w = p[7];
      *(uint4*)dst = qa;
      *(uint4*)(dst + 16) = qb;
    }
  } else {
    // ---- zero S: 65 blocks x 256 thr x 4 floats = 66560 ----
    int i = (bid - 418) * 1024 + tid * 4;
    float4 z; z.x = 0.f; z.y = 0.f; z.z = 0.f; z.w = 0.f;
    *(float4*)(S + i) = z;
    if (bid == 418 && tid == 0) out_loss[0] = 0.f;
  }
}

// ------------- H fp8 K=128 fragment-order, coalesced via LDS bounce -------------
// Hbf8 layout per bm tile: [kblk4][mg8][lane64*32B] (2048 B fragments);
// lane holds row = mg*16 + c16, k = kblk*128 + quad*32 + 0..31.
__global__ __launch_bounds__(256) void k_hf(const float* __restrict__ e,
                                            const float* __restrict__ dmatb,
                                            uchar_t* __restrict__ Hbf8){
  __shared__ uchar_t sH[16 * 520];    // 16 rows x 512 B, pad 8 B (8B-aligned reads)
  int tid = threadIdx.x;
  int wid = tid >> 6, lane = tid & 63;
  int c16 = lane & 15, quad = lane >> 4;
  int bm = blockIdx.x;
  int bu = bm >> 1, thalf = bm & 1;
  int b = bu / cU1;
  int t0 = thalf * 128;

  float dj[8];
  const float4* dp = (const float4*)(dmatb + (size_t)bu * cJ + lane * 8);
  float4 dA = dp[0], dB = dp[1];
  dj[0] = dA.x; dj[1] = dA.y; dj[2] = dA.z; dj[3] = dA.w;
  dj[4] = dB.x; dj[5] = dB.y; dj[6] = dB.z; dj[7] = dB.w;

  const float* erow0 = e + ((size_t)(b * cT + t0)) * cJ + lane * 8;
  uchar_t* outb = Hbf8 + (size_t)bm * 65536 + lane * 32;

  for (int mg = 0; mg < 8; mg++){
#pragma unroll
    for (int rr = 0; rr < 4; rr++){
      int rloc = wid * 4 + rr;
      const float* ep = erow0 + ((size_t)(mg * 16 + rloc)) * cJ;
      float4 e0 = *(const float4*)ep;
      float4 e1 = *(const float4*)(ep + 4);
      int v0 = pk8(tanh_fast(e0.x + dj[0]), tanh_fast(e0.y + dj[1]),
                   tanh_fast(e0.z + dj[2]), tanh_fast(e0.w + dj[3]));
      int v1 = pk8(tanh_fast(e1.x + dj[4]), tanh_fast(e1.y + dj[5]),
                   tanh_fast(e1.z + dj[6]), tanh_fast(e1.w + dj[7]));
      uint2 pk; pk.x = (unsigned)v0; pk.y = (unsigned)v1;
      *(uint2*)(sH + rloc * 520 + lane * 8) = pk;
    }
    __syncthreads();
    {
      int kblk = wid;                      // one K=128 fragment per wave
      const uchar_t* src = sH + c16 * 520 + kblk * 128 + quad * 32;
      uint2 q0 = *(const uint2*)(src);
      uint2 q1 = *(const uint2*)(src + 8);
      uint2 q2 = *(const uint2*)(src + 16);
      uint2 q3 = *(const uint2*)(src + 24);
      uint4 qa; qa.x = q0.x; qa.y = q0.y; qa.z = q1.x; qa.w = q1.y;
      uint4 qb; qb.x = q2.x; qb.y = q2.y; qb.z = q3.x; qb.w = q3.y;
      uchar_t* dst = outb + ((size_t)(kblk * 8 + mg)) * 2048;
      *(uint4*)(dst) = qa;
      *(uint4*)(dst + 16) = qb;
    }
    __syncthreads();
  }
}

// ------------- joint GEMM MX-fp8 K=128 (unit scales): 64x64 wave tile -------------
// r2 POST-MORTEM: __launch_bounds__(256,3) capped VGPRs at ~170; af[4]+bf[4]
// (64 VGPRs of v8i32 fragments) pushed the allocator into demoting them to
// SCRATCH -> 1.2 GB/dispatch of spill traffic (FETCH 702 MB, WRITE 469 MB),
// 282 us. Fix: (a) cap occupancy at 2 waves/EU -> 256-VGPR budget;
// (b) stream A-fragments (one af live at a time, bf[4] resident) so peak
// fragment liveness is 40 VGPRs; (c) unroll 1 on the kblk loop so the
// unroller can't hoist all 32 loads back into flight.
__global__ __launch_bounds__(256, 2) void k_joint(
    const uchar_t* __restrict__ Hbf8, const uchar_t* __restrict__ WTf8,
    const float* __restrict__ b_out, const int* __restrict__ targets,
    float* __restrict__ S,
    float* __restrict__ blank_g, float* __restrict__ lbl_g)
{
  __shared__ float redS[2][128];

  int tid = threadIdx.x;
  int wid = tid >> 6, lane = tid & 63;
  int quad = lane >> 4, c16 = lane & 15;
  int wm = wid & 1, wn = wid >> 1;
  int bid = blockIdx.x;
  int bm = ((bid >> 6) << 3) + (bid & 7);
  int bn = (bid >> 3) & 7;                       // 128-col strip
  int bu = bm >> 1, thalf = bm & 1;
  int b = bu / cU1, u = bu - b * cU1;
  int tg = (u < cU) ? targets[b * cU + u] : -1;
  int lin0 = bu * cT + thalf * 128;              // (b,u,t)-linear base

  f32x4 acc[4][4];
#pragma unroll
  for (int i = 0; i < 4; i++)
#pragma unroll
    for (int j = 0; j < 4; j++)
      acc[i][j] = (f32x4){0.f, 0.f, 0.f, 0.f};

  const uchar_t* aP = Hbf8 + (size_t)bm * 65536 + (size_t)(wm * 4) * 2048 + lane * 32;
  const uchar_t* bP = WTf8 + (size_t)bn * 65536 + (size_t)(wn * 4) * 2048 + lane * 32;

#pragma unroll 1
  for (int kblk = 0; kblk < 4; kblk++){
    const uchar_t* aK = aP + (size_t)kblk * 16384;
    const uchar_t* bK = bP + (size_t)kblk * 16384;
    v8i32 bf0 = *(const v8i32*)(bK);
    v8i32 bf1 = *(const v8i32*)(bK + 2048);
    v8i32 bf2 = *(const v8i32*)(bK + 4096);
    v8i32 bf3 = *(const v8i32*)(bK + 6144);
#pragma unroll
    for (int mt = 0; mt < 4; mt++){
      v8i32 af = *(const v8i32*)(aK + (size_t)mt * 2048);
      acc[mt][0] = __builtin_amdgcn_mfma_scale_f32_16x16x128_f8f6f4(
          af, bf0, acc[mt][0], 0, 0, 0, 0x7F7F7F7F, 0, 0x7F7F7F7F);
      acc[mt][1] = __builtin_amdgcn_mfma_scale_f32_16x16x128_f8f6f4(
          af, bf1, acc[mt][1], 0, 0, 0, 0x7F7F7F7F, 0, 0x7F7F7F7F);
      acc[mt][2] = __builtin_amdgcn_mfma_scale_f32_16x16x128_f8f6f4(
          af, bf2, acc[mt][2], 0, 0, 0, 0x7F7F7F7F, 0, 0x7F7F7F7F);
      acc[mt][3] = __builtin_amdgcn_mfma_scale_f32_16x16x128_f8f6f4(
          af, bf3, acc[mt][3], 0, 0, 0, 0x7F7F7F7F, 0, 0x7F7F7F7F);
    }
  }

  float bv[4];
#pragma unroll
  for (int nt = 0; nt < 4; nt++) bv[nt] = b_out[bn * 128 + (wn * 4 + nt) * 16 + c16] * LOG2E;

  bool ownL = (tg >= 0) && ((tg >> 7) == bn) && (((tg >> 6) & 1) == wn);
  int ntO = (tg >> 4) & 3;
  int tgc = tg & 15;
  const float descale2 = LOG2E / 32.f;  // undo *32 on W_out fp8 AND go log2-domain

#pragma unroll
  for (int mt = 0; mt < 4; mt++){
#pragma unroll
    for (int r = 0; r < 4; r++){
      int rl = wm * 64 + mt * 16 + quad * 4 + r;  // C/D: col=lane&15, row=quad*4+reg (m89)
      float l[4];
#pragma unroll
      for (int nt = 0; nt < 4; nt++) l[nt] = fmaf(acc[mt][nt][r], descale2, bv[nt]);
      if (bn == 0 && wn == 0 && c16 == 0) blank_g[lin0 + rl] = l[0];
      if (ownL && c16 == tgc){
        float v = l[0];
#pragma unroll
        for (int k = 1; k < 4; k++) v = (ntO == k) ? l[k] : v;
        lbl_g[lin0 + rl] = v;
      }
      float s = __builtin_amdgcn_exp2f(l[0]) + __builtin_amdgcn_exp2f(l[1])
              + __builtin_amdgcn_exp2f(l[2]) + __builtin_amdgcn_exp2f(l[3]);
      s += __shfl_xor(s, 1, 64);
      s += __shfl_xor(s, 2, 64);
      s += __shfl_xor(s, 4, 64);
      s += __shfl_xor(s, 8, 64);
      if (c16 == 0) redS[wn][rl] = s;
    }
  }
  __syncthreads();
  if (tid < 128)
    atomicAdd(&S[lin0 + tid], redS[0][tid] + redS[1][tid]);
}

// ------------- RNN-T alpha DP: SKIP-2 diagonals, log2 domain, fused-LSE staging -------------
// blank_g/lbl_g arrive ALREADY in log2 domain (k_joint epilogue) -> staging is
// just x - log2(S). Everything else as the verified r1 version.
__global__ __launch_bounds__(256) void k_dp(
    const float* __restrict__ S, const float* __restrict__ blank_g,
    const float* __restrict__ lbl_g,
    const int* __restrict__ in_len, const int* __restrict__ tgt_len,
    float* __restrict__ out)
{
  __shared__ float sbb[cTU];   // 65 KB, (u,t): index u*256+t  (log2 domain)
  __shared__ float slb[cTU];   // 65 KB
  __shared__ float sS[256];    // alpha[t][63] history (lane 63)
  int b = blockIdx.x;
  int tl  = tgt_len[b];                // 32..64
  size_t base = (size_t)b * cTU;
  for (int i = threadIdx.x; i < cTU / 4; i += 256){
    int row = i >> 6;                  // float4 never crosses a 256-elem row
    if (row > tl) continue;            // rows > tl unread by any live lane
    float4 sv = ((const float4*)(S + base))[i];
    float4 bvv = ((const float4*)(blank_g + base))[i];
    float4 ls;
    ls.x = __builtin_amdgcn_logf(sv.x); ls.y = __builtin_amdgcn_logf(sv.y);
    ls.z = __builtin_amdgcn_logf(sv.z); ls.w = __builtin_amdgcn_logf(sv.w);
    float4 bo;
    bo.x = bvv.x - ls.x; bo.y = bvv.y - ls.y;
    bo.z = bvv.z - ls.z; bo.w = bvv.w - ls.w;
    ((float4*)sbb)[i] = bo;
    float4 lo;
    if (row < tl){
      float4 lv = ((const float4*)(lbl_g + base))[i];
      lo.x = lv.x - ls.x; lo.y = lv.y - ls.y;
      lo.z = lv.z - ls.z; lo.w = lv.w - ls.w;
    } else {
      lo.x = NEGF; lo.y = NEGF; lo.z = NEGF; lo.w = NEGF;
    }
    ((float4*)slb)[i] = lo;
  }
  __syncthreads();
  if (threadIdx.x >= 64) return;

  int u = threadIdx.x;                 // 0..63
  int til = in_len[b] - 1;
  bool cap64 = (tl == 64);
  bool isTL = (u == tl);
  const float* pbu  = sbb + (u << 8);
  const float* pbu1 = sbb + (((u >= 1) ? u - 1 : 0) << 8);
  const float* plu1 = slb + (((u >= 1) ? u - 1 : 0) << 8);
  const float* plu2 = slb + (((u >= 2) ? u - 2 : 0) << 8);
  bool u1 = (u >= 1), u2 = (u >= 2);
  float fb = pbu[til];                 // blank at (u, til); used by lane tl only
  int shA1 = (u - 1) << 2;             // bpermute byte addrs; underflow wraps to
  int shA2 = (u - 2) << 2;             // lane 63 -> value killed by NEG masking

  float A = (u == 0) ? 0.f : NEGF;     // alpha on even diagonal d = 2g (log2)
  float res = 0.f;

  auto ld = [&](const float* p, int i, bool ok) -> float {
    float x = p[i & 255];              // wrap stays inside sbb/slb
    return (ok & ((unsigned)i < 256u)) ? x : NEGF;
  };

  int i0 = -u;
  float o0 = ld(pbu,  i0,     true);   // bb[t-2][u]
  float o1 = ld(pbu,  i0 + 1, true);   // bb[t-1][u]
  float o2 = ld(plu1, i0 + 1, u1);     // lb[t-1][u-1]
  float o3 = ld(pbu1, i0 + 1, u1);     // bb[t-1][u-1]
  float o4 = ld(plu1, i0 + 2, u1);     // lb[t][u-1]
  float o5 = ld(plu2, i0 + 2, u2);     // lb[t][u-2]

#pragma unroll 3
  for (int g = 0; g < 159; g++){
    // shuffles FIRST (depend on prev A) so the prefetch reads below stay behind
    // them in lgkm order -> waiting for up1/up2 is lgkmcnt(6), not a full drain
    float up1 = __int_as_float(__builtin_amdgcn_ds_bpermute(shA1, __float_as_int(A)));
    float up2 = __int_as_float(__builtin_amdgcn_ds_bpermute(shA2, __float_as_int(A)));

    int i0n = i0 + 2;
    float n0 = ld(pbu,  i0n,     true);
    float n1 = ld(pbu,  i0n + 1, true);
    float n2 = ld(plu1, i0n + 1, u1);
    float n3 = ld(pbu1, i0n + 1, u1);
    float n4 = ld(plu1, i0n + 2, u1);
    float n5 = ld(plu2, i0n + 2, u2);

    float C0 = o0 + o1;
    float C1 = logadd2(o2 + o1, o3 + o4);
    float C2 = o5 + o4;

    float am0 = A + o0, am1 = up1 + o2;
    float Amid = logadd2(am0, am1);
    bool tv1 = ((unsigned)(i0 + 1) < 256u);
    Amid = tv1 ? Amid : NEGF;

    float a0 = A + C0, a1 = up1 + C1, a2 = up2 + C2;
    float m3 = fmaxf(fmaxf(a0, a1), a2);          // v_max3
    float s3 = __builtin_amdgcn_exp2f(a0 - m3) + __builtin_amdgcn_exp2f(a1 - m3)
             + __builtin_amdgcn_exp2f(a2 - m3);
    float Anew = m3 + __builtin_amdgcn_logf(s3);
    bool tv2 = ((unsigned)(i0 + 2) < 256u);
    Anew = tv2 ? Anew : NEGF;

    if (isTL && (i0 + 1) == til) res = Amid + fb;
    if (isTL && (i0 + 2) == til) res = Anew + fb;
    if (u == 63){
      if (tv1) sS[i0 + 1] = Amid;
      if (tv2) sS[i0 + 2] = Anew;
    }
    A = Anew;
    i0 = i0n;
    o0 = n0; o1 = n1; o2 = n2; o3 = n3; o4 = n4; o5 = n5;
  }

  if (cap64){
    const float* pb64 = sbb + (64 << 8);
    const float* pl63 = slb + (63 << 8);
    float A64 = sS[0] + pl63[0];       // alpha[0][64]
    for (int t = 1; t <= til; t++)
      A64 = logadd2(A64 + pb64[t - 1], sS[t] + pl63[t]);
    if (u == 0) res = A64 + pb64[til];
  }

  // butterfly-sum broadcasts the single captured value (others hold 0)
  res += __shfl_xor(res, 1, 64);
  res += __shfl_xor(res, 2, 64);
  res += __shfl_xor(res, 4, 64);
  res += __shfl_xor(res, 8, 64);
  res += __shfl_xor(res, 16, 64);
  res += __shfl_xor(res, 32, 64);
  if (u == 0) atomicAdd(out, -0.17328679513998632f * res);  // -0.25 * ln2 (log2->ln)
}

extern "C" void kernel_launch(void* const* d_in, const int* in_sizes, int n_in,
                              void* d_out, int out_size, void* d_ws, size_t ws_size,
                              hipStream_t stream)
{
  (void)in_sizes; (void)n_in; (void)out_size; (void)ws_size;
  const float* inputs = (const float*)d_in[0];   // (4,256,80)
  const float* W_enc  = (const float*)d_in[1];   // (80,512)
  const float* emb    = (const float*)d_in[2];   // (1024,512)
  const float* W_jenc = (const float*)d_in[3];   // (512,512)
  const float* W_jdec = (const float*)d_in[4];   // (512,512)
  const float* b_j    = (const float*)d_in[5];   // (512)
  const float* W_out  = (const float*)d_in[6];   // (512,1024)
  const float* b_out  = (const float*)d_in[7];   // (1024)
  const int* targets  = (const int*)d_in[8];     // (4,64)
  const int* in_len   = (const int*)d_in[9];     // (4)
  const int* tgt_len  = (const int*)d_in[10];    // (4)

  char* w = (char*)d_ws;
  auto alloc = [&](size_t bytes){ char* p = w; w += (bytes + 255) & ~(size_t)255; return p; };
  float* e       = (float*)alloc((size_t)1024 * 512 * 4);
  float* dmatb   = (float*)alloc((size_t)260 * 512 * 4);
  float* blank_g = (float*)alloc((size_t)cM * 4);
  float* lbl_g   = (float*)alloc((size_t)cM * 4);
  float* S       = (float*)alloc((size_t)cM * 4);
  uchar_t* Hbf8  = (uchar_t*)alloc((size_t)520 * 65536);
  uchar_t* WTf8  = (uchar_t*)alloc((size_t)8 * 65536);

  k_pre<<<483, 256, 0, stream>>>(inputs, W_enc, W_jenc, emb, targets, W_jdec, b_j,
                                 dmatb, e, W_out, WTf8, S, (float*)d_out);
  k_hf<<<520, 256, 0, stream>>>(e, dmatb, Hbf8);
  k_joint<<<4160, 256, 0, stream>>>(Hbf8, WTf8, b_out, targets, S, blank_g, lbl_g);
  k_dp<<<4, 256, 0, stream>>>(S, blank_g, lbl_g, in_len, tgt_len, (float*)d_out);
}